// Round 1
// baseline (263.074 us; speedup 1.0000x reference)
//
#include <hip/hip_runtime.h>
#include <math.h>

#define B_ 512
#define V_ 50000
#define D_ 512
#define T_ 4
#define P_ 16
#define L_ 8
#define OUT_ 300

// ---------------------------------------------------------------------------
// K1: per (b,i,t) block. Compute 128 dots s[p][l] = <node_emb, feature_emb>,
// pw[p] = sum_l s[p][l], argmax_p (first max), masked softmax over l of
// s[p*][l], store selected emb row indices + coefficient tw * v[l] * w[l].
// ---------------------------------------------------------------------------
__global__ __launch_bounds__(256) void k1_score(
    const int* __restrict__ nodes, const int* __restrict__ features,
    const float* __restrict__ emb,
    const float* __restrict__ v, const float* __restrict__ w_rp,
    const float* __restrict__ w_ch, const float* __restrict__ w_on,
    int* __restrict__ wsIdx, float* __restrict__ wsCoef)
{
    const int g   = blockIdx.x;        // g = (b*2+i)*T + t
    const int t   = g & (T_ - 1);
    const int bi  = g >> 2;
    const int tid = threadIdx.x;
    const int wid = tid >> 6, lane = tid & 63;

    __shared__ float s_s[P_ * L_];     // 128 dot results

    const int nidx = nodes[bi];
    const float* nrow = emb + (size_t)nidx * D_;
    // per-lane node fragment (8 floats), reused for all 32 rows of this wave
    const float4 n0 = *(const float4*)(nrow + lane * 8);
    const float4 n1 = *(const float4*)(nrow + lane * 8 + 4);

    const int featBase = g * (P_ * L_);

    for (int j = 0; j < 32; j += 2) {
        const int rA = wid * 32 + j;
        const int rB = rA + 1;
        const int ia = features[featBase + rA];
        const int ib = features[featBase + rB];
        const float* ra = emb + (size_t)ia * D_ + lane * 8;
        const float* rb = emb + (size_t)ib * D_ + lane * 8;
        const float4 a0 = *(const float4*)ra;
        const float4 a1 = *(const float4*)(ra + 4);
        const float4 b0 = *(const float4*)rb;
        const float4 b1 = *(const float4*)(rb + 4);
        float accA = n0.x*a0.x + n0.y*a0.y + n0.z*a0.z + n0.w*a0.w
                   + n1.x*a1.x + n1.y*a1.y + n1.z*a1.z + n1.w*a1.w;
        float accB = n0.x*b0.x + n0.y*b0.y + n0.z*b0.z + n0.w*b0.w
                   + n1.x*b1.x + n1.y*b1.y + n1.z*b1.z + n1.w*b1.w;
        #pragma unroll
        for (int off = 32; off; off >>= 1) {
            accA += __shfl_down(accA, off);
            accB += __shfl_down(accB, off);
        }
        if (lane == 0) { s_s[rA] = accA; s_s[rB] = accB; }
    }
    __syncthreads();

    if (tid == 0) {
        // argmax over p of pw[p] = sum_l s[p][l]  (first-max like jnp.argmax)
        float best = -1e30f; int bp = 0;
        #pragma unroll
        for (int p = 0; p < P_; ++p) {
            float s = 0.f;
            #pragma unroll
            for (int l = 0; l < L_; ++l) s += s_s[p * L_ + l];
            if (s > best) { best = s; bp = p; }
        }
        // masked softmax over s[bp][0..7]
        float x[L_], m = -1e30f;
        #pragma unroll
        for (int l = 0; l < L_; ++l) {
            const float sv = s_s[bp * L_ + l];
            x[l] = sv + (sv == 0.0f ? -9999.0f : 0.0f);
            m = fmaxf(m, x[l]);
        }
        float e[L_], sum = 0.f;
        #pragma unroll
        for (int l = 0; l < L_; ++l) { e[l] = expf(x[l] - m); sum += e[l]; }
        const float wr = w_rp[0], wc = w_ch[0], wo = w_on[0];
        const float tw = (t == 0) ? wr : (t == 1) ? wc : (t == 2) ? wo
                                       : (1.0f - wr - wc - wo);
        const float inv = 1.0f / sum;
        #pragma unroll
        for (int l = 0; l < L_; ++l) {
            wsIdx [g * L_ + l] = features[featBase + bp * L_ + l];
            wsCoef[g * L_ + l] = tw * v[l] * (e[l] * inv);
        }
    }
}

// ---------------------------------------------------------------------------
// K2: per (b,i) block. context[d] = sum over 32 selected rows coef*emb[row][d];
// writes contextual = [node_emb | context] (1024 floats).
// ---------------------------------------------------------------------------
__global__ __launch_bounds__(256) void k2_context(
    const int* __restrict__ nodes, const float* __restrict__ emb,
    const int* __restrict__ wsIdx, const float* __restrict__ wsCoef,
    float* __restrict__ cont)
{
    const int bi  = blockIdx.x;
    const int tid = threadIdx.x;
    float a0 = 0.f, a1 = 0.f;
    #pragma unroll 4
    for (int r = 0; r < 32; ++r) {
        const int   idx = wsIdx [bi * 32 + r];
        const float c   = wsCoef[bi * 32 + r];
        const float* row = emb + (size_t)idx * D_;
        a0 += c * row[tid];
        a1 += c * row[tid + 256];
    }
    const int nidx = nodes[bi];
    const float* nrow = emb + (size_t)nidx * D_;
    float* cp = cont + (size_t)bi * 1024;
    cp[tid]            = nrow[tid];
    cp[tid + 256]      = nrow[tid + 256];
    cp[512 + tid]       = a0;
    cp[512 + tid + 256] = a1;
}

// ---------------------------------------------------------------------------
// K3: fused GEMM (contextual @ W_out^T + b_out) + per-b cosine -> sim_ent.
// 4 b's (8 contextual vectors) per block, staged in LDS.
// ---------------------------------------------------------------------------
__global__ __launch_bounds__(256) void k3_gemm_cos(
    const float* __restrict__ cont, const float* __restrict__ W,
    const float* __restrict__ bias, float* __restrict__ out)
{
    const int bb  = blockIdx.x;       // handles b = bb*4 .. bb*4+3
    const int tid = threadIdx.x;
    const int wid = tid >> 6, lane = tid & 63;

    __shared__ float cs[8][1024];     // 32 KB
    __shared__ float red[4][12];

    for (int k = tid; k < 8 * 1024; k += 256) {
        const int vec = k >> 10, d = k & 1023;
        cs[vec][d] = cont[(size_t)(bb * 8 + vec) * 1024 + d];
    }
    __syncthreads();

    float sab[4] = {0,0,0,0}, saa[4] = {0,0,0,0}, sbb[4] = {0,0,0,0};

    for (int o = wid; o < OUT_; o += 4) {
        const float* wrow = W + (size_t)o * 1024;
        float wv[16];
        #pragma unroll
        for (int k = 0; k < 16; ++k) wv[k] = wrow[lane + 64 * k];
        float dot[8];
        #pragma unroll
        for (int vv = 0; vv < 8; ++vv) {
            float acc = 0.f;
            #pragma unroll
            for (int k = 0; k < 16; ++k) acc += wv[k] * cs[vv][lane + 64 * k];
            dot[vv] = acc;
        }
        #pragma unroll
        for (int vv = 0; vv < 8; ++vv) {
            #pragma unroll
            for (int off = 32; off; off >>= 1) dot[vv] += __shfl_down(dot[vv], off);
        }
        if (lane == 0) {
            const float bo = bias[o];
            #pragma unroll
            for (int j = 0; j < 4; ++j) {
                const float r0 = dot[2*j]   + bo;
                const float r1 = dot[2*j+1] + bo;
                sab[j] += r0 * r1; saa[j] += r0 * r0; sbb[j] += r1 * r1;
            }
        }
    }
    if (lane == 0) {
        #pragma unroll
        for (int j = 0; j < 4; ++j) {
            red[wid][j*3+0] = sab[j];
            red[wid][j*3+1] = saa[j];
            red[wid][j*3+2] = sbb[j];
        }
    }
    __syncthreads();
    if (tid < 4) {
        const int j = tid;
        float ab = 0.f, aa = 0.f, bbv = 0.f;
        for (int w2 = 0; w2 < 4; ++w2) {
            ab  += red[w2][j*3+0];
            aa  += red[w2][j*3+1];
            bbv += red[w2][j*3+2];
        }
        const float na = fmaxf(sqrtf(aa),  1e-8f);
        const float nb = fmaxf(sqrtf(bbv), 1e-8f);
        out[bb * 4 + j] = ab / (na * nb);
    }
}

// ---------------------------------------------------------------------------
// K4: property branch. Per b: 6 aggregates (sum of 32 emb rows) in LDS,
// 3 cosines, weighted combine -> sim_prop -> out[B + b].
// ---------------------------------------------------------------------------
__global__ __launch_bounds__(256) void k4_prop(
    const int* __restrict__ pf, const float* __restrict__ emb,
    const float* __restrict__ pw_, const float* __restrict__ dw_,
    float* __restrict__ out)
{
    const int b   = blockIdx.x;
    const int tid = threadIdx.x;
    const int wid = tid >> 6, lane = tid & 63;

    __shared__ float agg[6][512];     // 12 KB
    __shared__ float red[4][9];

    for (int g = 0; g < 6; ++g) {
        const int i = g / 3, j = g % 3;
        const int base = ((b * 2 + i) * 3 + j) * 32;
        float a0 = 0.f, a1 = 0.f;
        #pragma unroll 4
        for (int k = 0; k < 32; ++k) {
            const int idx = pf[base + k];
            const float* row = emb + (size_t)idx * D_;
            a0 += row[tid];
            a1 += row[tid + 256];
        }
        agg[g][tid]       = a0;
        agg[g][tid + 256] = a1;
    }
    __syncthreads();

    float p[9];
    #pragma unroll
    for (int j = 0; j < 3; ++j) {
        const float* A  = agg[j];
        const float* Bv = agg[3 + j];
        const float a0 = A[tid], a1 = A[tid + 256];
        const float b0 = Bv[tid], b1 = Bv[tid + 256];
        p[j*3+0] = a0 * b0 + a1 * b1;
        p[j*3+1] = a0 * a0 + a1 * a1;
        p[j*3+2] = b0 * b0 + b1 * b1;
    }
    #pragma unroll
    for (int q = 0; q < 9; ++q) {
        #pragma unroll
        for (int off = 32; off; off >>= 1) p[q] += __shfl_down(p[q], off);
    }
    if (lane == 0) {
        #pragma unroll
        for (int q = 0; q < 9; ++q) red[wid][q] = p[q];
    }
    __syncthreads();
    if (tid == 0) {
        float s[9];
        #pragma unroll
        for (int q = 0; q < 9; ++q)
            s[q] = red[0][q] + red[1][q] + red[2][q] + red[3][q];
        float cosv[3];
        #pragma unroll
        for (int j = 0; j < 3; ++j) {
            const float na = fmaxf(sqrtf(s[j*3+1]), 1e-8f);
            const float nb = fmaxf(sqrtf(s[j*3+2]), 1e-8f);
            cosv[j] = s[j*3+0] / (na * nb);
        }
        const float pw = pw_[0], dw = dw_[0];
        out[B_ + b] = pw * cosv[0] + dw * cosv[1] + (1.0f - pw - dw) * cosv[2];
    }
}

// ---------------------------------------------------------------------------
extern "C" void kernel_launch(void* const* d_in, const int* in_sizes, int n_in,
                              void* d_out, int out_size, void* d_ws, size_t ws_size,
                              hipStream_t stream) {
    const int*   nodes   = (const int*)  d_in[0];
    const int*   features= (const int*)  d_in[1];
    // d_in[2] = prop_nodes (unused by reference)
    const int*   propf   = (const int*)  d_in[3];
    const float* emb     = (const float*)d_in[4];
    const float* W_out   = (const float*)d_in[5];
    const float* b_out   = (const float*)d_in[6];
    const float* v       = (const float*)d_in[7];
    const float* w_rp    = (const float*)d_in[8];
    const float* w_ch    = (const float*)d_in[9];
    const float* w_on    = (const float*)d_in[10];
    const float* pw      = (const float*)d_in[11];
    const float* dw      = (const float*)d_in[12];
    float* out = (float*)d_out;

    // workspace layout
    char* ws = (char*)d_ws;
    int*   wsIdx  = (int*)  ws;                              // 32768 ints
    float* wsCoef = (float*)(ws + 32768 * sizeof(int));      // 32768 floats
    float* cont   = (float*)(ws + 2 * 32768 * sizeof(int));  // 1024*1024 floats

    k1_score<<<B_ * 2 * T_, 256, 0, stream>>>(nodes, features, emb, v,
                                              w_rp, w_ch, w_on, wsIdx, wsCoef);
    k2_context<<<B_ * 2, 256, 0, stream>>>(nodes, emb, wsIdx, wsCoef, cont);
    k3_gemm_cos<<<B_ / 4, 256, 0, stream>>>(cont, W_out, b_out, out);
    k4_prop<<<B_, 256, 0, stream>>>(propf, emb, pw, dw, out);
}